// Round 7
// baseline (424.638 us; speedup 1.0000x reference)
//
#include <hip/hip_runtime.h>
#include <math.h>

#define B_   2
#define L_   1024
#define DM   1024
#define DS   16
#define DC   4
#define DI   2048          // E*DM
#define DR   64            // DM/16
#define NTOK (B_*L_)       // 2048
#define EPSF 1e-5f
#define NC   32            // scan chunks
#define CL   (L_/NC)       // 32 steps per chunk
#define SPLITS 8           // x_proj K-splits

typedef __bf16 bf16_t;
typedef bf16_t bf16x4 __attribute__((ext_vector_type(4)));
typedef bf16_t bf16x8 __attribute__((ext_vector_type(8)));
typedef float  f32x4  __attribute__((ext_vector_type(4)));

__device__ __forceinline__ float siluf(float x){ return x / (1.f + __expf(-x)); }
__device__ __forceinline__ float softplusf(float x){ return (x > 20.f) ? x : log1pf(__expf(x)); }

__device__ __forceinline__ void gload_lds16(const void* g, void* l) {
    __builtin_amdgcn_global_load_lds(
        (const __attribute__((address_space(1))) void*)g,
        (__attribute__((address_space(3))) void*)l, 16, 0, 0);
}

// value-returning split (vector elements can't bind to references)
struct hl_t { bf16_t h, l; };
__device__ __forceinline__ hl_t split2(float v) {
    hl_t r;
    r.h = (bf16_t)v;
    r.l = (bf16_t)(v - (float)r.h);
    return r;
}

// ======= launch 1: RMSNorm (blocks 0..2047) + all weight splits ============
#define SPLIT_IN_BLKS  ((2*DI*DM/4)/256)   // 8192
#define SPLIT_DT_BLKS  ((DI*DR/4)/256)     // 128
#define SPLIT_X_BLKS   ((128*DI/4)/256)    // 256
__global__ __launch_bounds__(256) void rms_split_all(
    const float* __restrict__ x, const float* __restrict__ w,
    bf16_t* __restrict__ uh, bf16_t* __restrict__ ul,
    const float* __restrict__ in_w, bf16_t* __restrict__ wih, bf16_t* __restrict__ wil,
    const float* __restrict__ dt_w, bf16_t* __restrict__ wdth, bf16_t* __restrict__ wdtl,
    const float* __restrict__ x_w,  bf16_t* __restrict__ wxh,  bf16_t* __restrict__ wxl)
{
    __shared__ float sred[4];
    int blk = blockIdx.x;
    int t = threadIdx.x;

    if (blk < NTOK) {                       // ---- RMSNorm row ----
        int row = blk;
        float4 v = ((const float4*)(x + (size_t)row*DM))[t];
        float ss = v.x*v.x + v.y*v.y + v.z*v.z + v.w*v.w;
        #pragma unroll
        for (int off = 32; off > 0; off >>= 1) ss += __shfl_xor(ss, off, 64);
        if ((t & 63) == 0) sred[t >> 6] = ss;
        __syncthreads();
        ss = sred[0] + sred[1] + sred[2] + sred[3];
        float rs = rsqrtf(ss * (1.f/(float)DM) + EPSF);
        float4 wv = ((const float4*)w)[t];
        float o[4];
        o[0] = v.x*rs*wv.x; o[1] = v.y*rs*wv.y; o[2] = v.z*rs*wv.z; o[3] = v.w*rs*wv.w;
        bf16x4 hv, lv;
        #pragma unroll
        for (int j = 0; j < 4; ++j) { hl_t s = split2(o[j]); hv[j] = s.h; lv[j] = s.l; }
        *(bf16x4*)(uh + (size_t)row*DM + t*4) = hv;
        *(bf16x4*)(ul + (size_t)row*DM + t*4) = lv;
        return;
    }
    blk -= NTOK;
    if (blk < SPLIT_IN_BLKS) {              // ---- in_proj_w ----
        int i = blk * 256 + t;
        float4 v = ((const float4*)in_w)[i];
        float o[4] = {v.x, v.y, v.z, v.w};
        bf16x4 hv, lv;
        #pragma unroll
        for (int j = 0; j < 4; ++j) { hl_t s = split2(o[j]); hv[j] = s.h; lv[j] = s.l; }
        ((bf16x4*)wih)[i] = hv;
        ((bf16x4*)wil)[i] = lv;
        return;
    }
    blk -= SPLIT_IN_BLKS;
    if (blk < SPLIT_DT_BLKS) {              // ---- dt_proj_w ----
        int i = blk * 256 + t;
        float4 v = ((const float4*)dt_w)[i];
        float o[4] = {v.x, v.y, v.z, v.w};
        bf16x4 hv, lv;
        #pragma unroll
        for (int j = 0; j < 4; ++j) { hl_t s = split2(o[j]); hv[j] = s.h; lv[j] = s.l; }
        ((bf16x4*)wdth)[i] = hv;
        ((bf16x4*)wdtl)[i] = lv;
        return;
    }
    blk -= SPLIT_DT_BLKS;
    {                                       // ---- x_proj_w padded 96->128 ----
        int i = blk * 256 + t;              // over 128*DI/4
        int row = i >> 9;                   // DI/4 = 512 float4 per row
        bf16x4 hv, lv;
        if (row < 96) {
            float4 v = ((const float4*)x_w)[i];
            float o[4] = {v.x, v.y, v.z, v.w};
            #pragma unroll
            for (int j = 0; j < 4; ++j) { hl_t s = split2(o[j]); hv[j] = s.h; lv[j] = s.l; }
        } else {
            #pragma unroll
            for (int j = 0; j < 4; ++j) { hv[j] = (bf16_t)0.f; lv[j] = (bf16_t)0.f; }
        }
        ((bf16x4*)wxh)[i] = hv;
        ((bf16x4*)wxl)[i] = lv;
    }
}

// ---------------- split-bf16 MFMA NT GEMM, 2-phase double-buffered ---------
// C[M,N](fp32) = (Ah+Al)[M,K] * (Bh+Bl)[N,K]^T ; 3 MFMAs per fragment pair.
// NOTE: 16B-slot XOR swizzle (source-side per rule #21, matching read XOR) is
// correctness-consistent but perf-neutral here: with 64B rows there are only
// 4 slots, so 8 lanes/bank-group is structural at this tile shape.
template<int BN, int EPI, bool SK>
__global__ __launch_bounds__(256) void gemm_mfma(
    const bf16_t* __restrict__ Ah, const bf16_t* __restrict__ Al,
    const bf16_t* __restrict__ Bh, const bf16_t* __restrict__ Bl,
    float* __restrict__ C, int ldc,
    const float* __restrict__ res, const float* __restrict__ bias,
    int M, int N, int K, int kspl)
{
    constexpr int NJ   = BN / 32;
    constexpr int WN   = BN / 2;
    constexpr int ACH  = 8;
    constexpr int BCH  = BN / 16;
    constexpr int NCH  = 2*ACH + 2*BCH;
    constexpr int PERW = NCH / 4;
    constexpr int AOFF_L = 128*32;
    constexpr int BOFF_H = 2*128*32;
    constexpr int BOFF_L = 2*128*32 + BN*32;
    constexpr int BUFSZ  = 2*128*32 + 2*BN*32;

    __shared__ bf16_t lds[2*BUFSZ];

    int t = threadIdx.x;
    int w = t >> 6, lane = t & 63;
    int wr = w >> 1, wc = w & 1;
    int m0 = blockIdx.y * 128;
    int n0 = SK ? 0 : blockIdx.x * BN;
    int k0beg = SK ? blockIdx.x * kspl : 0;
    int nst = (SK ? kspl : K) >> 5;
    float* Cp = C;
    if (SK) Cp += (size_t)blockIdx.x * M * BN;

    f32x4 acc[4][NJ];
    #pragma unroll
    for (int i = 0; i < 4; ++i)
        #pragma unroll
        for (int j = 0; j < NJ; ++j)
            acc[i][j] = (f32x4){0.f, 0.f, 0.f, 0.f};

    int lrow = lane >> 2;                              // row within 16-row chunk
    int lcol = (((lane & 3) ^ ((lane >> 3) & 3)) * 8); // swizzled source chunk
    int ar   = wr*64 + (lane & 15);
    int br   = wc*WN + (lane & 15);
    int koff = (((lane >> 4) ^ ((lane >> 1) & 3)) * 8); // matching read slot

    auto STAGE = [&](int buf, int k0) {
        int base = buf ? BUFSZ : 0;
        #pragma unroll
        for (int q = 0; q < PERW; ++q) {
            int ch = w * PERW + q;
            const bf16_t* g; int le;
            if (ch < ACH) {
                int cc = ch;
                g  = Ah + (size_t)(m0 + cc*16 + lrow)*K + k0 + lcol;
                le = cc*512 + lane*8;
            } else if (ch < 2*ACH) {
                int cc = ch - ACH;
                g  = Al + (size_t)(m0 + cc*16 + lrow)*K + k0 + lcol;
                le = AOFF_L + cc*512 + lane*8;
            } else if (ch < 2*ACH + BCH) {
                int cc = ch - 2*ACH;
                g  = Bh + (size_t)(n0 + cc*16 + lrow)*K + k0 + lcol;
                le = BOFF_H + cc*512 + lane*8;
            } else {
                int cc = ch - 2*ACH - BCH;
                g  = Bl + (size_t)(n0 + cc*16 + lrow)*K + k0 + lcol;
                le = BOFF_L + cc*512 + lane*8;
            }
            gload_lds16(g, &lds[base + le]);
        }
    };

    STAGE(0, k0beg);
    __syncthreads();
    int cur = 0;
    for (int s = 0; s < nst; ++s) {
        int k0 = k0beg + (s << 5);
        if (s + 1 < nst) STAGE(cur ^ 1, k0 + 32);
        int base = cur ? BUFSZ : 0;

        bf16x8 ah[4], al4[4], bh[NJ], bl4[NJ];
        #pragma unroll
        for (int i = 0; i < 4; ++i) {
            ah[i]  = *(const bf16x8*)&lds[base + (ar + i*16)*32 + koff];
            al4[i] = *(const bf16x8*)&lds[base + AOFF_L + (ar + i*16)*32 + koff];
        }
        #pragma unroll
        for (int j = 0; j < NJ; ++j) {
            bh[j]  = *(const bf16x8*)&lds[base + BOFF_H + (br + j*16)*32 + koff];
            bl4[j] = *(const bf16x8*)&lds[base + BOFF_L + (br + j*16)*32 + koff];
        }
        #pragma unroll
        for (int i = 0; i < 4; ++i)
            #pragma unroll
            for (int j = 0; j < NJ; ++j) {
                acc[i][j] = __builtin_amdgcn_mfma_f32_16x16x32_bf16(ah[i],  bh[j],  acc[i][j], 0, 0, 0);
                acc[i][j] = __builtin_amdgcn_mfma_f32_16x16x32_bf16(al4[i], bh[j],  acc[i][j], 0, 0, 0);
                acc[i][j] = __builtin_amdgcn_mfma_f32_16x16x32_bf16(ah[i],  bl4[j], acc[i][j], 0, 0, 0);
            }
        __syncthreads();
        cur ^= 1;
    }

    // epilogue: C/D layout col=lane&15, row=(lane>>4)*4+reg  [m89-verified]
    int rb = m0 + wr*64 + (lane >> 4)*4;
    int cb = n0 + wc*WN + (lane & 15);
    #pragma unroll
    for (int i = 0; i < 4; ++i)
        #pragma unroll
        for (int j = 0; j < NJ; ++j) {
            int col = cb + j*16;
            float bcol = (EPI == 1) ? bias[col] : 0.f;
            #pragma unroll
            for (int r = 0; r < 4; ++r) {
                int row = rb + i*16 + r;
                float v = acc[i][j][r];
                if (EPI == 1) v = softplusf(v + bcol);
                if (EPI == 2) v += res[(size_t)row*ldc + col];
                Cp[(size_t)row*ldc + col] = v;
            }
        }
}

// ======= launch 5: x_proj split-K reduce (blocks 0..255) + out_proj_w split =
__global__ __launch_bounds__(256) void reduce_split_o(
    const float* __restrict__ parts,
    bf16_t* __restrict__ dth, bf16_t* __restrict__ dtl,
    float* __restrict__ bc,
    const float* __restrict__ out_w,
    bf16_t* __restrict__ woh, bf16_t* __restrict__ wol)
{
    int blk = blockIdx.x;
    int t = threadIdx.x;
    if (blk < (NTOK*32)/256) {              // ---- reduce ----
        int idx = blk * 256 + t;
        int m  = idx >> 5;
        int c  = (idx & 31) * 4;
        float4 s = {0.f, 0.f, 0.f, 0.f};
        #pragma unroll
        for (int sp = 0; sp < SPLITS; ++sp) {
            float4 v = *(const float4*)(parts + ((size_t)sp*NTOK + m)*128 + c);
            s.x += v.x; s.y += v.y; s.z += v.z; s.w += v.w;
        }
        if (c < 64) {
            float o[4] = {s.x, s.y, s.z, s.w};
            bf16x4 hv, lv;
            #pragma unroll
            for (int j = 0; j < 4; ++j) { hl_t sp2 = split2(o[j]); hv[j] = sp2.h; lv[j] = sp2.l; }
            *(bf16x4*)(dth + (size_t)m*DR + c) = hv;
            *(bf16x4*)(dtl + (size_t)m*DR + c) = lv;
        } else if (c < 96) {
            *(float4*)(bc + (size_t)m*32 + (c - 64)) = s;
        }
        return;
    }
    blk -= (NTOK*32)/256;
    {                                       // ---- out_proj_w split ----
        int i = blk * 256 + t;              // over DM*DI/4
        float4 v = ((const float4*)out_w)[i];
        float o[4] = {v.x, v.y, v.z, v.w};
        bf16x4 hv, lv;
        #pragma unroll
        for (int j = 0; j < 4; ++j) { hl_t s = split2(o[j]); hv[j] = s.h; lv[j] = s.l; }
        ((bf16x4*)woh)[i] = hv;
        ((bf16x4*)wol)[i] = lv;
    }
}

// ------- causal depthwise conv (DC=4) + bias + SiLU -> split bf16 ----------
__global__ __launch_bounds__(256) void conv_silu_k(const float* __restrict__ xz,
                                                   const float* __restrict__ cw,
                                                   const float* __restrict__ cb,
                                                   bf16_t* __restrict__ xch,
                                                   bf16_t* __restrict__ xcl)
{
    int idx = blockIdx.x * 256 + threadIdx.x;
    int d4 = idx & (DI/4 - 1);
    int m  = idx >> 9;
    int l  = m & (L_ - 1);
    int d  = d4 * 4;

    float4 w0 = *(const float4*)(cw + (size_t)(d+0)*DC);
    float4 w1 = *(const float4*)(cw + (size_t)(d+1)*DC);
    float4 w2 = *(const float4*)(cw + (size_t)(d+2)*DC);
    float4 w3 = *(const float4*)(cw + (size_t)(d+3)*DC);
    float wr0[4] = {w0.x,w0.y,w0.z,w0.w};
    float wr1[4] = {w1.x,w1.y,w1.z,w1.w};
    float wr2[4] = {w2.x,w2.y,w2.z,w2.w};
    float wr3[4] = {w3.x,w3.y,w3.z,w3.w};
    float4 bias = *(const float4*)(cb + d);
    float a0 = bias.x, a1 = bias.y, a2 = bias.z, a3 = bias.w;

    #pragma unroll
    for (int j = 0; j < DC; ++j) {
        int tt = l - (DC-1) + j;
        if (tt < 0) continue;
        float4 xv = *(const float4*)(xz + (size_t)(m - l + tt)*(2*DI) + d);
        a0 = fmaf(wr0[j], xv.x, a0);
        a1 = fmaf(wr1[j], xv.y, a1);
        a2 = fmaf(wr2[j], xv.z, a2);
        a3 = fmaf(wr3[j], xv.w, a3);
    }
    float o[4] = { siluf(a0), siluf(a1), siluf(a2), siluf(a3) };
    bf16x4 hv, lv;
    #pragma unroll
    for (int j = 0; j < 4; ++j) { hl_t s = split2(o[j]); hv[j] = s.h; lv[j] = s.l; }
    *(bf16x4*)(xch + (size_t)m*DI + d) = hv;
    *(bf16x4*)(xcl + (size_t)m*DI + d) = lv;
}

// ---------------- chunked selective scan (NC=32 chunks of CL=32) -----------
// Phase 1: per-chunk partial state H[16] from h=0, plus S = sum(delta).
__global__ __launch_bounds__(256) void scan_p1(const float* __restrict__ delta,
                                               const bf16_t* __restrict__ xch,
                                               const bf16_t* __restrict__ xcl,
                                               const float* __restrict__ bc,
                                               const float* __restrict__ A_log,
                                               float* __restrict__ Sbuf,
                                               float* __restrict__ Hbuf)
{
    __shared__ float Bsh[CL][16];
    int t = threadIdx.x;
    int blk = blockIdx.x;                 // b*(NC*8) + c*8 + dblk
    int d = (blk & 7) * 256 + t;
    int c = (blk >> 3) & (NC - 1);
    int b = blk >> 8;
    int m0 = b * L_ + c * CL;

    for (int i = t; i < CL*16; i += 256)
        Bsh[i >> 4][i & 15] = bc[(size_t)(m0 + (i >> 4))*32 + (i & 15)];
    __syncthreads();

    float A[16], h[16];
    #pragma unroll
    for (int j = 0; j < 4; ++j) {
        float4 al = *(const float4*)(A_log + (size_t)d*DS + j*4);
        A[j*4+0] = -__expf(al.x); A[j*4+1] = -__expf(al.y);
        A[j*4+2] = -__expf(al.z); A[j*4+3] = -__expf(al.w);
    }
    #pragma unroll
    for (int n = 0; n < 16; ++n) h[n] = 0.f;
    float S = 0.f;

    #pragma unroll 4
    for (int tt = 0; tt < CL; ++tt) {
        int m = m0 + tt;
        float dv = delta[(size_t)m*DI + d];
        float xv = (float)xch[(size_t)m*DI + d] + (float)xcl[(size_t)m*DI + d];
        float dx = dv * xv;
        S += dv;
        #pragma unroll
        for (int n = 0; n < 16; ++n) {
            float dA = __expf(dv * A[n]);
            h[n] = fmaf(dA, h[n], Bsh[tt][n] * dx);
        }
    }

    Sbuf[(size_t)(b*NC + c)*DI + d] = S;
    size_t o = ((size_t)((b*NC + c)*DI) + d) * DS;
    #pragma unroll
    for (int j = 0; j < 4; ++j) {
        float4 hv;
        hv.x = h[j*4+0]; hv.y = h[j*4+1]; hv.z = h[j*4+2]; hv.w = h[j*4+3];
        *(float4*)(Hbuf + o + j*4) = hv;
    }
}

// Phase 2: scan chunk summaries per (b,d,n); P = exp(A*S) recomputed;
// Hbuf rewritten IN PLACE with h0 entering each chunk.
__global__ __launch_bounds__(256) void scan_p2(const float* __restrict__ Sbuf,
                                               float* __restrict__ Hbuf,
                                               const float* __restrict__ A_log)
{
    int idx = blockIdx.x * 256 + threadIdx.x;   // (b, d, n)
    int n = idx & 15;
    int d = (idx >> 4) & (DI - 1);
    int b = idx >> 15;
    float Areg = -__expf(A_log[(size_t)d*DS + n]);
    float h = 0.f;
    #pragma unroll
    for (int c = 0; c < NC; ++c) {
        size_t so = (size_t)(b*NC + c)*DI + d;
        size_t o  = so * DS + n;
        float P  = __expf(Areg * Sbuf[so]);
        float hh = Hbuf[o];
        Hbuf[o] = h;                 // h0 entering chunk c
        h = fmaf(P, h, hh);
    }
}

// Phase 3: replay chunk from h0, emit g = (y + xc*D)*silu(z) as split bf16.
__global__ __launch_bounds__(256) void scan_p3(const float* __restrict__ delta,
                                               const float* __restrict__ xz,
                                               const bf16_t* __restrict__ xch,
                                               const bf16_t* __restrict__ xcl,
                                               const float* __restrict__ bc,
                                               const float* __restrict__ A_log,
                                               const float* __restrict__ Dp,
                                               const float* __restrict__ h0buf,
                                               bf16_t* __restrict__ gh,
                                               bf16_t* __restrict__ gl)
{
    __shared__ float Bsh[CL][16];
    __shared__ float Csh[CL][16];
    int t = threadIdx.x;
    int blk = blockIdx.x;
    int d = (blk & 7) * 256 + t;
    int c = (blk >> 3) & (NC - 1);
    int b = blk >> 8;
    int m0 = b * L_ + c * CL;

    for (int i = t; i < CL*16; i += 256) {
        int tt = i >> 4, n = i & 15;
        size_t ro = (size_t)(m0 + tt)*32;
        Bsh[tt][n] = bc[ro + n];
        Csh[tt][n] = bc[ro + 16 + n];
    }
    __syncthreads();

    float A[16], h[16];
    #pragma unroll
    for (int j = 0; j < 4; ++j) {
        float4 al = *(const float4*)(A_log + (size_t)d*DS + j*4);
        A[j*4+0] = -__expf(al.x); A[j*4+1] = -__expf(al.y);
        A[j*4+2] = -__expf(al.z); A[j*4+3] = -__expf(al.w);
    }
    size_t o = ((size_t)((b*NC + c)*DI) + d) * DS;
    #pragma unroll
    for (int j = 0; j < 4; ++j) {
        float4 hv = *(const float4*)(h0buf + o + j*4);
        h[j*4+0] = hv.x; h[j*4+1] = hv.y; h[j*4+2] = hv.z; h[j*4+3] = hv.w;
    }
    float Dreg = Dp[d];

    for (int t0 = 0; t0 < CL; t0 += 4) {
        float dv[4], xv[4], zv[4];
        #pragma unroll
        for (int q = 0; q < 4; ++q) {
            int m = m0 + t0 + q;
            dv[q] = delta[(size_t)m*DI + d];
            xv[q] = (float)xch[(size_t)m*DI + d] + (float)xcl[(size_t)m*DI + d];
            zv[q] = xz[(size_t)m*(2*DI) + DI + d];
        }
        #pragma unroll
        for (int q = 0; q < 4; ++q) {
            int tt = t0 + q, m = m0 + tt;
            float dx = dv[q] * xv[q];
            float y = 0.f;
            #pragma unroll
            for (int n = 0; n < 16; ++n) {
                float dA = __expf(dv[q] * A[n]);
                h[n] = fmaf(dA, h[n], Bsh[tt][n] * dx);
                y = fmaf(h[n], Csh[tt][n], y);
            }
            float gv = (y + xv[q]*Dreg) * siluf(zv[q]);
            hl_t s = split2(gv);
            gh[(size_t)m*DI + d] = s.h;
            gl[(size_t)m*DI + d] = s.l;
        }
    }
}

extern "C" void kernel_launch(void* const* d_in, const int* in_sizes, int n_in,
                              void* d_out, int out_size, void* d_ws, size_t ws_size,
                              hipStream_t stream)
{
    const float* x         = (const float*)d_in[0];
    const float* norm_w    = (const float*)d_in[1];
    const float* in_proj_w = (const float*)d_in[2];
    const float* conv_w    = (const float*)d_in[3];
    const float* conv_b    = (const float*)d_in[4];
    const float* x_proj_w  = (const float*)d_in[5];
    const float* dt_proj_w = (const float*)d_in[6];
    const float* dt_proj_b = (const float*)d_in[7];
    const float* A_log     = (const float*)d_in[8];
    const float* Dp        = (const float*)d_in[9];
    const float* out_proj_w= (const float*)d_in[10];
    float* out = (float*)d_out;

    char* p = (char*)d_ws;
    float*  xz    = (float*)p;  p += (size_t)NTOK*2*DI*4;    // 33.55 MB
    bf16_t* xch   = (bf16_t*)p; p += (size_t)NTOK*DI*2;      //  8.39 MB
    bf16_t* xcl   = (bf16_t*)p; p += (size_t)NTOK*DI*2;      //  8.39 MB
    float*  delta = (float*)p;  p += (size_t)NTOK*DI*4;      // 16.78 MB
    float*  bc    = (float*)p;  p += (size_t)NTOK*32*4;      //  0.26 MB
    bf16_t* dth   = (bf16_t*)p; p += (size_t)NTOK*DR*2;      //  0.26 MB
    bf16_t* dtl   = (bf16_t*)p; p += (size_t)NTOK*DR*2;      //  0.26 MB
    float*  Hbuf  = (float*)p;  p += (size_t)B_*NC*DI*DS*4;  //  8.39 MB (also uh/ul, parts)
    char*   Wreg  = p;          p += (size_t)2*DI*DM*2*2;    // 16.78 MB (wih/wil -> gh/gl)
    bf16_t* woh   = (bf16_t*)p; p += (size_t)DM*DI*2;        //  4.19 MB (dedicated)
    bf16_t* wol   = (bf16_t*)p; p += (size_t)DM*DI*2;        //  4.19 MB (dedicated)
    float*  Sbuf  = (float*)p;  p += (size_t)B_*NC*DI*4;     //  0.52 MB (dedicated)
    bf16_t* wxh   = (bf16_t*)p; p += (size_t)128*DI*2;       //  0.52 MB
    bf16_t* wxl   = (bf16_t*)p; p += (size_t)128*DI*2;       //  0.52 MB
    bf16_t* wdth  = (bf16_t*)p; p += (size_t)DI*DR*2;        //  0.26 MB
    bf16_t* wdtl  = (bf16_t*)p; p += (size_t)DI*DR*2;        //  0.26 MB
    // total ~103.5 MB

    // Hbuf region staged reuse: uh/ul (8.39MB, pre-in_proj) -> parts (8.39MB,
    // x_proj partials) -> H/h0 (8.39MB, scan). Each lifetime ends before next.
    bf16_t* uh  = (bf16_t*)Hbuf;
    bf16_t* ul  = uh + (size_t)NTOK*DM;
    float*  parts = Hbuf;
    // Wreg: wih/wil (in_proj weights, dead after step 2) -> gh/gl (step 7+)
    bf16_t* wih = (bf16_t*)Wreg;
    bf16_t* wil = wih + (size_t)2*DI*DM;
    bf16_t* gh  = (bf16_t*)Wreg;
    bf16_t* gl  = gh + (size_t)NTOK*DI;

    // 1. RMSNorm + all weight splits (one launch)
    rms_split_all<<<NTOK + SPLIT_IN_BLKS + SPLIT_DT_BLKS + SPLIT_X_BLKS, 256, 0, stream>>>(
        x, norm_w, uh, ul, in_proj_w, wih, wil,
        dt_proj_w, wdth, wdtl, x_proj_w, wxh, wxl);

    // 2. in_proj (MFMA): xz[2048,4096] = u @ in_proj_w^T
    gemm_mfma<128,0,false><<<dim3((2*DI)/128, NTOK/128), 256, 0, stream>>>(
        uh, ul, wih, wil, xz, 2*DI, nullptr, nullptr, NTOK, 2*DI, DM, 0);

    // 3. causal depthwise conv + SiLU -> split bf16 xc
    conv_silu_k<<<(NTOK*(DI/4))/256, 256, 0, stream>>>(xz, conv_w, conv_b, xch, xcl);

    // 4. x_proj (MFMA, split-K over K=2048): parts[8][2048][128]
    gemm_mfma<128,0,true><<<dim3(SPLITS, NTOK/128), 256, 0, stream>>>(
        xch, xcl, wxh, wxl, parts, 128, nullptr, nullptr, NTOK, 128, DI, DI/SPLITS);

    // 5. reduce partials (-> dt split + bc) + out_proj_w split (one launch)
    reduce_split_o<<<(NTOK*32)/256 + (DM*DI/4)/256, 256, 0, stream>>>(
        parts, dth, dtl, bc, out_proj_w, woh, wol);

    // 6. dt_proj (MFMA, K=64) + softplus + bias -> delta fp32
    gemm_mfma<128,1,false><<<dim3(DI/128, NTOK/128), 256, 0, stream>>>(
        dth, dtl, wdth, wdtl, delta, DI, nullptr, dt_proj_b, NTOK, DI, DR, 0);

    // 7. chunked selective scan
    scan_p1<<<B_*NC*(DI/256), 256, 0, stream>>>(delta, xch, xcl, bc, A_log, Sbuf, Hbuf);
    scan_p2<<<(B_*DI*DS)/256, 256, 0, stream>>>(Sbuf, Hbuf, A_log);
    scan_p3<<<B_*NC*(DI/256), 256, 0, stream>>>(delta, xz, xch, xcl, bc, A_log, Dp,
                                                Hbuf, gh, gl);

    // 8. out_proj (MFMA) + residual: out = g @ out_proj_w^T + x
    gemm_mfma<64,2,false><<<dim3(DM/64, NTOK/128), 256, 0, stream>>>(
        gh, gl, woh, wol, out, DM, x, nullptr, NTOK, DM, DI, 0);
}

// Round 8
// 357.502 us; speedup vs baseline: 1.1878x; 1.1878x over previous
//
#include <hip/hip_runtime.h>
#include <math.h>

#define B_   2
#define L_   1024
#define DM   1024
#define DS   16
#define DC   4
#define DI   2048          // E*DM
#define DR   64            // DM/16
#define NTOK (B_*L_)       // 2048
#define EPSF 1e-5f
#define NC   32            // scan chunks
#define CL   (L_/NC)       // 32 steps per chunk
#define SPLITS 8           // x_proj K-splits

typedef __bf16 bf16_t;
typedef bf16_t bf16x4 __attribute__((ext_vector_type(4)));
typedef bf16_t bf16x8 __attribute__((ext_vector_type(8)));
typedef float  f32x4  __attribute__((ext_vector_type(4)));

__device__ __forceinline__ float siluf(float x){ return x / (1.f + __expf(-x)); }
__device__ __forceinline__ float softplusf(float x){ return (x > 20.f) ? x : log1pf(__expf(x)); }

__device__ __forceinline__ void gload_lds16(const void* g, void* l) {
    __builtin_amdgcn_global_load_lds(
        (const __attribute__((address_space(1))) void*)g,
        (__attribute__((address_space(3))) void*)l, 16, 0, 0);
}

// value-returning split (vector elements can't bind to references)
struct hl_t { bf16_t h, l; };
__device__ __forceinline__ hl_t split2(float v) {
    hl_t r;
    r.h = (bf16_t)v;
    r.l = (bf16_t)(v - (float)r.h);
    return r;
}

// ======= launch 1: RMSNorm (blocks 0..2047) + in_proj/x_proj weight splits ==
#define SPLIT_IN_BLKS  ((2*DI*DM/4)/256)   // 8192
#define SPLIT_X_BLKS   ((128*DI/4)/256)    // 256
__global__ __launch_bounds__(256) void rms_split_all(
    const float* __restrict__ x, const float* __restrict__ w,
    bf16_t* __restrict__ uh, bf16_t* __restrict__ ul,
    const float* __restrict__ in_w, bf16_t* __restrict__ wih, bf16_t* __restrict__ wil,
    const float* __restrict__ x_w,  bf16_t* __restrict__ wxh,  bf16_t* __restrict__ wxl)
{
    __shared__ float sred[4];
    int blk = blockIdx.x;
    int t = threadIdx.x;

    if (blk < NTOK) {                       // ---- RMSNorm row ----
        int row = blk;
        float4 v = ((const float4*)(x + (size_t)row*DM))[t];
        float ss = v.x*v.x + v.y*v.y + v.z*v.z + v.w*v.w;
        #pragma unroll
        for (int off = 32; off > 0; off >>= 1) ss += __shfl_xor(ss, off, 64);
        if ((t & 63) == 0) sred[t >> 6] = ss;
        __syncthreads();
        ss = sred[0] + sred[1] + sred[2] + sred[3];
        float rs = rsqrtf(ss * (1.f/(float)DM) + EPSF);
        float4 wv = ((const float4*)w)[t];
        float o[4];
        o[0] = v.x*rs*wv.x; o[1] = v.y*rs*wv.y; o[2] = v.z*rs*wv.z; o[3] = v.w*rs*wv.w;
        bf16x4 hv, lv;
        #pragma unroll
        for (int j = 0; j < 4; ++j) { hl_t s = split2(o[j]); hv[j] = s.h; lv[j] = s.l; }
        *(bf16x4*)(uh + (size_t)row*DM + t*4) = hv;
        *(bf16x4*)(ul + (size_t)row*DM + t*4) = lv;
        return;
    }
    blk -= NTOK;
    if (blk < SPLIT_IN_BLKS) {              // ---- in_proj_w ----
        int i = blk * 256 + t;
        float4 v = ((const float4*)in_w)[i];
        float o[4] = {v.x, v.y, v.z, v.w};
        bf16x4 hv, lv;
        #pragma unroll
        for (int j = 0; j < 4; ++j) { hl_t s = split2(o[j]); hv[j] = s.h; lv[j] = s.l; }
        ((bf16x4*)wih)[i] = hv;
        ((bf16x4*)wil)[i] = lv;
        return;
    }
    blk -= SPLIT_IN_BLKS;
    {                                       // ---- x_proj_w padded 96->128 ----
        int i = blk * 256 + t;              // over 128*DI/4
        int row = i >> 9;                   // DI/4 = 512 float4 per row
        bf16x4 hv, lv;
        if (row < 96) {
            float4 v = ((const float4*)x_w)[i];
            float o[4] = {v.x, v.y, v.z, v.w};
            #pragma unroll
            for (int j = 0; j < 4; ++j) { hl_t s = split2(o[j]); hv[j] = s.h; lv[j] = s.l; }
        } else {
            #pragma unroll
            for (int j = 0; j < 4; ++j) { hv[j] = (bf16_t)0.f; lv[j] = (bf16_t)0.f; }
        }
        ((bf16x4*)wxh)[i] = hv;
        ((bf16x4*)wxl)[i] = lv;
    }
}

// ---------------- split-bf16 MFMA NT GEMM, 2-phase double-buffered ---------
// EXACT round-4 form (no LDS swizzle — swizzle A/B'd at −2x on dt_proj, r7).
// C[M,N](fp32) = (Ah+Al)[M,K] * (Bh+Bl)[N,K]^T ; 3 MFMAs per fragment pair.
template<int BN, int EPI, bool SK>
__global__ __launch_bounds__(256) void gemm_mfma(
    const bf16_t* __restrict__ Ah, const bf16_t* __restrict__ Al,
    const bf16_t* __restrict__ Bh, const bf16_t* __restrict__ Bl,
    float* __restrict__ C, int ldc,
    const float* __restrict__ res, const float* __restrict__ bias,
    int M, int N, int K, int kspl)
{
    constexpr int NJ   = BN / 32;
    constexpr int WN   = BN / 2;
    constexpr int ACH  = 8;
    constexpr int BCH  = BN / 16;
    constexpr int NCH  = 2*ACH + 2*BCH;
    constexpr int PERW = NCH / 4;
    constexpr int AOFF_L = 128*32;
    constexpr int BOFF_H = 2*128*32;
    constexpr int BOFF_L = 2*128*32 + BN*32;
    constexpr int BUFSZ  = 2*128*32 + 2*BN*32;

    __shared__ bf16_t lds[2*BUFSZ];

    int t = threadIdx.x;
    int w = t >> 6, lane = t & 63;
    int wr = w >> 1, wc = w & 1;
    int m0 = blockIdx.y * 128;
    int n0 = SK ? 0 : blockIdx.x * BN;
    int k0beg = SK ? blockIdx.x * kspl : 0;
    int nst = (SK ? kspl : K) >> 5;
    float* Cp = C;
    if (SK) Cp += (size_t)blockIdx.x * M * BN;

    f32x4 acc[4][NJ];
    #pragma unroll
    for (int i = 0; i < 4; ++i)
        #pragma unroll
        for (int j = 0; j < NJ; ++j)
            acc[i][j] = (f32x4){0.f, 0.f, 0.f, 0.f};

    int lrow = lane >> 2;          // row within 16-row chunk
    int lcol = (lane & 3) * 8;     // k element offset (LINEAR, r4-proven)
    int ar   = wr*64 + (lane & 15);
    int br   = wc*WN + (lane & 15);
    int koff = (lane >> 4) * 8;

    auto STAGE = [&](int buf, int k0) {
        int base = buf ? BUFSZ : 0;
        #pragma unroll
        for (int q = 0; q < PERW; ++q) {
            int ch = w * PERW + q;
            const bf16_t* g; int le;
            if (ch < ACH) {
                int cc = ch;
                g  = Ah + (size_t)(m0 + cc*16 + lrow)*K + k0 + lcol;
                le = cc*512 + lane*8;
            } else if (ch < 2*ACH) {
                int cc = ch - ACH;
                g  = Al + (size_t)(m0 + cc*16 + lrow)*K + k0 + lcol;
                le = AOFF_L + cc*512 + lane*8;
            } else if (ch < 2*ACH + BCH) {
                int cc = ch - 2*ACH;
                g  = Bh + (size_t)(n0 + cc*16 + lrow)*K + k0 + lcol;
                le = BOFF_H + cc*512 + lane*8;
            } else {
                int cc = ch - 2*ACH - BCH;
                g  = Bl + (size_t)(n0 + cc*16 + lrow)*K + k0 + lcol;
                le = BOFF_L + cc*512 + lane*8;
            }
            gload_lds16(g, &lds[base + le]);
        }
    };

    STAGE(0, k0beg);
    __syncthreads();
    int cur = 0;
    for (int s = 0; s < nst; ++s) {
        int k0 = k0beg + (s << 5);
        if (s + 1 < nst) STAGE(cur ^ 1, k0 + 32);
        int base = cur ? BUFSZ : 0;

        bf16x8 ah[4], al4[4], bh[NJ], bl4[NJ];
        #pragma unroll
        for (int i = 0; i < 4; ++i) {
            ah[i]  = *(const bf16x8*)&lds[base + (ar + i*16)*32 + koff];
            al4[i] = *(const bf16x8*)&lds[base + AOFF_L + (ar + i*16)*32 + koff];
        }
        #pragma unroll
        for (int j = 0; j < NJ; ++j) {
            bh[j]  = *(const bf16x8*)&lds[base + BOFF_H + (br + j*16)*32 + koff];
            bl4[j] = *(const bf16x8*)&lds[base + BOFF_L + (br + j*16)*32 + koff];
        }
        #pragma unroll
        for (int i = 0; i < 4; ++i)
            #pragma unroll
            for (int j = 0; j < NJ; ++j) {
                acc[i][j] = __builtin_amdgcn_mfma_f32_16x16x32_bf16(ah[i],  bh[j],  acc[i][j], 0, 0, 0);
                acc[i][j] = __builtin_amdgcn_mfma_f32_16x16x32_bf16(al4[i], bh[j],  acc[i][j], 0, 0, 0);
                acc[i][j] = __builtin_amdgcn_mfma_f32_16x16x32_bf16(ah[i],  bl4[j], acc[i][j], 0, 0, 0);
            }
        __syncthreads();
        cur ^= 1;
    }

    // epilogue: C/D layout col=lane&15, row=(lane>>4)*4+reg  [m89-verified]
    int rb = m0 + wr*64 + (lane >> 4)*4;
    int cb = n0 + wc*WN + (lane & 15);
    #pragma unroll
    for (int i = 0; i < 4; ++i)
        #pragma unroll
        for (int j = 0; j < NJ; ++j) {
            int col = cb + j*16;
            #pragma unroll
            for (int r = 0; r < 4; ++r) {
                int row = rb + i*16 + r;
                float v = acc[i][j][r];
                if (EPI == 2) v += res[(size_t)row*ldc + col];
                Cp[(size_t)row*ldc + col] = v;
            }
        }
}

// ======= launch 5: x_proj reduce + FUSED dt_proj matvec + out_proj_w split ==
// blocks [0, 256): 8 tokens each — phase A: reduce split-K partials into
//   LDS dt[8][64] + write bc; phase B: delta[tok][d] = softplus(dt·Wdt^T + b)
//   in exact fp32 (d = dd*256 + t -> coalesced stores, W rows L2-resident,
//   LDS reads are wave-broadcast).
// blocks [256, 256+2048): out_proj_w split.
__global__ __launch_bounds__(256) void reduce_dt(
    const float* __restrict__ parts,
    float* __restrict__ bc,
    const float* __restrict__ dt_w,     // [DI, DR] fp32
    const float* __restrict__ dt_b,     // [DI]
    float* __restrict__ delta,          // [NTOK, DI]
    const float* __restrict__ out_w,
    bf16_t* __restrict__ woh, bf16_t* __restrict__ wol)
{
    int blk = blockIdx.x;
    int t = threadIdx.x;
    if (blk < NTOK/8) {
        __shared__ float dtsh[8][DR];       // 2 KB
        int token = t >> 5;                 // 0..7
        int c = (t & 31) * 4;               // 0..124
        int m = blk*8 + token;
        float4 s = {0.f, 0.f, 0.f, 0.f};
        #pragma unroll
        for (int sp = 0; sp < SPLITS; ++sp) {
            float4 v = *(const float4*)(parts + ((size_t)sp*NTOK + m)*128 + c);
            s.x += v.x; s.y += v.y; s.z += v.z; s.w += v.w;
        }
        if (c < 64) {
            *(float4*)&dtsh[token][c] = s;
        } else if (c < 96) {
            *(float4*)(bc + (size_t)m*32 + (c - 64)) = s;
        }
        __syncthreads();
        // phase B: 8 d-columns per thread, all 8 tokens
        for (int dd = 0; dd < 8; ++dd) {
            int d = dd*256 + t;
            float4 wv[16];
            #pragma unroll
            for (int k4 = 0; k4 < 16; ++k4)
                wv[k4] = *(const float4*)(dt_w + (size_t)d*DR + k4*4);
            float bb = dt_b[d];
            float acc[8];
            #pragma unroll
            for (int tok = 0; tok < 8; ++tok) acc[tok] = bb;
            #pragma unroll
            for (int k4 = 0; k4 < 16; ++k4) {
                #pragma unroll
                for (int tok = 0; tok < 8; ++tok) {
                    acc[tok] = fmaf(wv[k4].x, dtsh[tok][k4*4+0], acc[tok]);
                    acc[tok] = fmaf(wv[k4].y, dtsh[tok][k4*4+1], acc[tok]);
                    acc[tok] = fmaf(wv[k4].z, dtsh[tok][k4*4+2], acc[tok]);
                    acc[tok] = fmaf(wv[k4].w, dtsh[tok][k4*4+3], acc[tok]);
                }
            }
            #pragma unroll
            for (int tok = 0; tok < 8; ++tok)
                delta[(size_t)(blk*8 + tok)*DI + d] = softplusf(acc[tok]);
        }
        return;
    }
    blk -= NTOK/8;
    {                                       // ---- out_proj_w split ----
        int i = blk * 256 + t;              // over DM*DI/4
        float4 v = ((const float4*)out_w)[i];
        float o[4] = {v.x, v.y, v.z, v.w};
        bf16x4 hv, lv;
        #pragma unroll
        for (int j = 0; j < 4; ++j) { hl_t s = split2(o[j]); hv[j] = s.h; lv[j] = s.l; }
        ((bf16x4*)woh)[i] = hv;
        ((bf16x4*)wol)[i] = lv;
    }
}

// ------- causal depthwise conv (DC=4) + bias + SiLU -> split bf16 ----------
__global__ __launch_bounds__(256) void conv_silu_k(const float* __restrict__ xz,
                                                   const float* __restrict__ cw,
                                                   const float* __restrict__ cb,
                                                   bf16_t* __restrict__ xch,
                                                   bf16_t* __restrict__ xcl)
{
    int idx = blockIdx.x * 256 + threadIdx.x;
    int d4 = idx & (DI/4 - 1);
    int m  = idx >> 9;
    int l  = m & (L_ - 1);
    int d  = d4 * 4;

    float4 w0 = *(const float4*)(cw + (size_t)(d+0)*DC);
    float4 w1 = *(const float4*)(cw + (size_t)(d+1)*DC);
    float4 w2 = *(const float4*)(cw + (size_t)(d+2)*DC);
    float4 w3 = *(const float4*)(cw + (size_t)(d+3)*DC);
    float wr0[4] = {w0.x,w0.y,w0.z,w0.w};
    float wr1[4] = {w1.x,w1.y,w1.z,w1.w};
    float wr2[4] = {w2.x,w2.y,w2.z,w2.w};
    float wr3[4] = {w3.x,w3.y,w3.z,w3.w};
    float4 bias = *(const float4*)(cb + d);
    float a0 = bias.x, a1 = bias.y, a2 = bias.z, a3 = bias.w;

    #pragma unroll
    for (int j = 0; j < DC; ++j) {
        int tt = l - (DC-1) + j;
        if (tt < 0) continue;
        float4 xv = *(const float4*)(xz + (size_t)(m - l + tt)*(2*DI) + d);
        a0 = fmaf(wr0[j], xv.x, a0);
        a1 = fmaf(wr1[j], xv.y, a1);
        a2 = fmaf(wr2[j], xv.z, a2);
        a3 = fmaf(wr3[j], xv.w, a3);
    }
    float o[4] = { siluf(a0), siluf(a1), siluf(a2), siluf(a3) };
    bf16x4 hv, lv;
    #pragma unroll
    for (int j = 0; j < 4; ++j) { hl_t s = split2(o[j]); hv[j] = s.h; lv[j] = s.l; }
    *(bf16x4*)(xch + (size_t)m*DI + d) = hv;
    *(bf16x4*)(xcl + (size_t)m*DI + d) = lv;
}

// ---------------- chunked selective scan (NC=32 chunks of CL=32) -----------
__global__ __launch_bounds__(256) void scan_p1(const float* __restrict__ delta,
                                               const bf16_t* __restrict__ xch,
                                               const bf16_t* __restrict__ xcl,
                                               const float* __restrict__ bc,
                                               const float* __restrict__ A_log,
                                               float* __restrict__ Sbuf,
                                               float* __restrict__ Hbuf)
{
    __shared__ float Bsh[CL][16];
    int t = threadIdx.x;
    int blk = blockIdx.x;                 // b*(NC*8) + c*8 + dblk
    int d = (blk & 7) * 256 + t;
    int c = (blk >> 3) & (NC - 1);
    int b = blk >> 8;
    int m0 = b * L_ + c * CL;

    for (int i = t; i < CL*16; i += 256)
        Bsh[i >> 4][i & 15] = bc[(size_t)(m0 + (i >> 4))*32 + (i & 15)];
    __syncthreads();

    float A[16], h[16];
    #pragma unroll
    for (int j = 0; j < 4; ++j) {
        float4 al = *(const float4*)(A_log + (size_t)d*DS + j*4);
        A[j*4+0] = -__expf(al.x); A[j*4+1] = -__expf(al.y);
        A[j*4+2] = -__expf(al.z); A[j*4+3] = -__expf(al.w);
    }
    #pragma unroll
    for (int n = 0; n < 16; ++n) h[n] = 0.f;
    float S = 0.f;

    #pragma unroll 4
    for (int tt = 0; tt < CL; ++tt) {
        int m = m0 + tt;
        float dv = delta[(size_t)m*DI + d];
        float xv = (float)xch[(size_t)m*DI + d] + (float)xcl[(size_t)m*DI + d];
        float dx = dv * xv;
        S += dv;
        #pragma unroll
        for (int n = 0; n < 16; ++n) {
            float dA = __expf(dv * A[n]);
            h[n] = fmaf(dA, h[n], Bsh[tt][n] * dx);
        }
    }

    Sbuf[(size_t)(b*NC + c)*DI + d] = S;
    size_t o = ((size_t)((b*NC + c)*DI) + d) * DS;
    #pragma unroll
    for (int j = 0; j < 4; ++j) {
        float4 hv;
        hv.x = h[j*4+0]; hv.y = h[j*4+1]; hv.z = h[j*4+2]; hv.w = h[j*4+3];
        *(float4*)(Hbuf + o + j*4) = hv;
    }
}

// Phase 2: scan chunk summaries per (b,d,n); P = exp(A*S) recomputed;
// Hbuf rewritten IN PLACE with h0 entering each chunk.
__global__ __launch_bounds__(256) void scan_p2(const float* __restrict__ Sbuf,
                                               float* __restrict__ Hbuf,
                                               const float* __restrict__ A_log)
{
    int idx = blockIdx.x * 256 + threadIdx.x;   // (b, d, n)
    int n = idx & 15;
    int d = (idx >> 4) & (DI - 1);
    int b = idx >> 15;
    float Areg = -__expf(A_log[(size_t)d*DS + n]);
    float h = 0.f;
    #pragma unroll
    for (int c = 0; c < NC; ++c) {
        size_t so = (size_t)(b*NC + c)*DI + d;
        size_t o  = so * DS + n;
        float P  = __expf(Areg * Sbuf[so]);
        float hh = Hbuf[o];
        Hbuf[o] = h;                 // h0 entering chunk c
        h = fmaf(P, h, hh);
    }
}

// Phase 3: replay chunk from h0, emit g = (y + xc*D)*silu(z) as split bf16.
__global__ __launch_bounds__(256) void scan_p3(const float* __restrict__ delta,
                                               const float* __restrict__ xz,
                                               const bf16_t* __restrict__ xch,
                                               const bf16_t* __restrict__ xcl,
                                               const float* __restrict__ bc,
                                               const float* __restrict__ A_log,
                                               const float* __restrict__ Dp,
                                               const float* __restrict__ h0buf,
                                               bf16_t* __restrict__ gh,
                                               bf16_t* __restrict__ gl)
{
    __shared__ float Bsh[CL][16];
    __shared__ float Csh[CL][16];
    int t = threadIdx.x;
    int blk = blockIdx.x;
    int d = (blk & 7) * 256 + t;
    int c = (blk >> 3) & (NC - 1);
    int b = blk >> 8;
    int m0 = b * L_ + c * CL;

    for (int i = t; i < CL*16; i += 256) {
        int tt = i >> 4, n = i & 15;
        size_t ro = (size_t)(m0 + tt)*32;
        Bsh[tt][n] = bc[ro + n];
        Csh[tt][n] = bc[ro + 16 + n];
    }
    __syncthreads();

    float A[16], h[16];
    #pragma unroll
    for (int j = 0; j < 4; ++j) {
        float4 al = *(const float4*)(A_log + (size_t)d*DS + j*4);
        A[j*4+0] = -__expf(al.x); A[j*4+1] = -__expf(al.y);
        A[j*4+2] = -__expf(al.z); A[j*4+3] = -__expf(al.w);
    }
    size_t o = ((size_t)((b*NC + c)*DI) + d) * DS;
    #pragma unroll
    for (int j = 0; j < 4; ++j) {
        float4 hv = *(const float4*)(h0buf + o + j*4);
        h[j*4+0] = hv.x; h[j*4+1] = hv.y; h[j*4+2] = hv.z; h[j*4+3] = hv.w;
    }
    float Dreg = Dp[d];

    for (int t0 = 0; t0 < CL; t0 += 4) {
        float dv[4], xv[4], zv[4];
        #pragma unroll
        for (int q = 0; q < 4; ++q) {
            int m = m0 + t0 + q;
            dv[q] = delta[(size_t)m*DI + d];
            xv[q] = (float)xch[(size_t)m*DI + d] + (float)xcl[(size_t)m*DI + d];
            zv[q] = xz[(size_t)m*(2*DI) + DI + d];
        }
        #pragma unroll
        for (int q = 0; q < 4; ++q) {
            int tt = t0 + q, m = m0 + tt;
            float dx = dv[q] * xv[q];
            float y = 0.f;
            #pragma unroll
            for (int n = 0; n < 16; ++n) {
                float dA = __expf(dv[q] * A[n]);
                h[n] = fmaf(dA, h[n], Bsh[tt][n] * dx);
                y = fmaf(h[n], Csh[tt][n], y);
            }
            float gv = (y + xv[q]*Dreg) * siluf(zv[q]);
            hl_t s = split2(gv);
            gh[(size_t)m*DI + d] = s.h;
            gl[(size_t)m*DI + d] = s.l;
        }
    }
}

extern "C" void kernel_launch(void* const* d_in, const int* in_sizes, int n_in,
                              void* d_out, int out_size, void* d_ws, size_t ws_size,
                              hipStream_t stream)
{
    const float* x         = (const float*)d_in[0];
    const float* norm_w    = (const float*)d_in[1];
    const float* in_proj_w = (const float*)d_in[2];
    const float* conv_w    = (const float*)d_in[3];
    const float* conv_b    = (const float*)d_in[4];
    const float* x_proj_w  = (const float*)d_in[5];
    const float* dt_proj_w = (const float*)d_in[6];
    const float* dt_proj_b = (const float*)d_in[7];
    const float* A_log     = (const float*)d_in[8];
    const float* Dp        = (const float*)d_in[9];
    const float* out_proj_w= (const float*)d_in[10];
    float* out = (float*)d_out;

    char* p = (char*)d_ws;
    float*  xz    = (float*)p;  p += (size_t)NTOK*2*DI*4;    // 33.55 MB
    bf16_t* xch   = (bf16_t*)p; p += (size_t)NTOK*DI*2;      //  8.39 MB
    bf16_t* xcl   = (bf16_t*)p; p += (size_t)NTOK*DI*2;      //  8.39 MB
    float*  delta = (float*)p;  p += (size_t)NTOK*DI*4;      // 16.78 MB
    float*  bc    = (float*)p;  p += (size_t)NTOK*32*4;      //  0.26 MB
    float*  Hbuf  = (float*)p;  p += (size_t)B_*NC*DI*DS*4;  //  8.39 MB (also uh/ul, parts)
    char*   Wreg  = p;          p += (size_t)2*DI*DM*2*2;    // 16.78 MB (wih/wil -> gh/gl)
    bf16_t* woh   = (bf16_t*)p; p += (size_t)DM*DI*2;        //  4.19 MB (dedicated)
    bf16_t* wol   = (bf16_t*)p; p += (size_t)DM*DI*2;        //  4.19 MB (dedicated)
    float*  Sbuf  = (float*)p;  p += (size_t)B_*NC*DI*4;     //  0.52 MB (dedicated)
    bf16_t* wxh   = (bf16_t*)p; p += (size_t)128*DI*2;       //  0.52 MB
    bf16_t* wxl   = (bf16_t*)p; p += (size_t)128*DI*2;       //  0.52 MB
    // total ~102.5 MB

    // Hbuf region staged reuse: uh/ul (pre-in_proj) -> parts (x_proj partials)
    // -> H/h0 (scan). Each lifetime ends before the next begins.
    bf16_t* uh  = (bf16_t*)Hbuf;
    bf16_t* ul  = uh + (size_t)NTOK*DM;
    float*  parts = Hbuf;
    // Wreg: wih/wil (in_proj weights, dead after step 2) -> gh/gl (step 6+)
    bf16_t* wih = (bf16_t*)Wreg;
    bf16_t* wil = wih + (size_t)2*DI*DM;
    bf16_t* gh  = (bf16_t*)Wreg;
    bf16_t* gl  = gh + (size_t)NTOK*DI;

    // 1. RMSNorm + in_proj/x_proj weight splits (one launch)
    rms_split_all<<<NTOK + SPLIT_IN_BLKS + SPLIT_X_BLKS, 256, 0, stream>>>(
        x, norm_w, uh, ul, in_proj_w, wih, wil, x_proj_w, wxh, wxl);

    // 2. in_proj (MFMA): xz[2048,4096] = u @ in_proj_w^T
    gemm_mfma<128,0,false><<<dim3((2*DI)/128, NTOK/128), 256, 0, stream>>>(
        uh, ul, wih, wil, xz, 2*DI, nullptr, nullptr, NTOK, 2*DI, DM, 0);

    // 3. causal depthwise conv + SiLU -> split bf16 xc
    conv_silu_k<<<(NTOK*(DI/4))/256, 256, 0, stream>>>(xz, conv_w, conv_b, xch, xcl);

    // 4. x_proj (MFMA, split-K over K=2048): parts[8][2048][128]
    gemm_mfma<128,0,true><<<dim3(SPLITS, NTOK/128), 256, 0, stream>>>(
        xch, xcl, wxh, wxl, parts, 128, nullptr, nullptr, NTOK, 128, DI, DI/SPLITS);

    // 5. reduce partials + FUSED dt_proj matvec (fp32) + out_proj_w split
    reduce_dt<<<NTOK/8 + (DM*DI/4)/256, 256, 0, stream>>>(
        parts, bc, dt_proj_w, dt_proj_b, delta, out_proj_w, woh, wol);

    // 6. chunked selective scan
    scan_p1<<<B_*NC*(DI/256), 256, 0, stream>>>(delta, xch, xcl, bc, A_log, Sbuf, Hbuf);
    scan_p2<<<(B_*DI*DS)/256, 256, 0, stream>>>(Sbuf, Hbuf, A_log);
    scan_p3<<<B_*NC*(DI/256), 256, 0, stream>>>(delta, xz, xch, xcl, bc, A_log, Dp,
                                                Hbuf, gh, gl);

    // 7. out_proj (MFMA) + residual: out = g @ out_proj_w^T + x
    gemm_mfma<64,2,false><<<dim3(DM/64, NTOK/128), 256, 0, stream>>>(
        gh, gl, woh, wol, out, DM, x, nullptr, NTOK, DM, DI, 0);
}

// Round 9
// 330.526 us; speedup vs baseline: 1.2847x; 1.0816x over previous
//
#include <hip/hip_runtime.h>
#include <math.h>

#define B_   2
#define L_   1024
#define DM   1024
#define DS   16
#define DC   4
#define DI   2048          // E*DM
#define DR   64            // DM/16
#define NTOK (B_*L_)       // 2048
#define EPSF 1e-5f
#define NC   32            // scan chunks
#define CL   (L_/NC)       // 32 steps per chunk
#define SPLITS 8           // x_proj K-splits

typedef __bf16 bf16_t;
typedef bf16_t bf16x4 __attribute__((ext_vector_type(4)));
typedef bf16_t bf16x8 __attribute__((ext_vector_type(8)));
typedef float  f32x4  __attribute__((ext_vector_type(4)));

__device__ __forceinline__ float siluf(float x){ return x / (1.f + __expf(-x)); }
__device__ __forceinline__ float softplusf(float x){ return (x > 20.f) ? x : log1pf(__expf(x)); }

__device__ __forceinline__ void gload_lds16(const void* g, void* l) {
    __builtin_amdgcn_global_load_lds(
        (const __attribute__((address_space(1))) void*)g,
        (__attribute__((address_space(3))) void*)l, 16, 0, 0);
}

// value-returning split (vector elements can't bind to references)
struct hl_t { bf16_t h, l; };
__device__ __forceinline__ hl_t split2(float v) {
    hl_t r;
    r.h = (bf16_t)v;
    r.l = (bf16_t)(v - (float)r.h);
    return r;
}

// ==== launch 1: RMSNorm (blocks 0..2047) + ALL weight splits (incl out_w) ===
#define SPLIT_IN_BLKS  ((2*DI*DM/4)/256)   // 8192
#define SPLIT_X_BLKS   ((128*DI/4)/256)    // 256
#define SPLIT_O_BLKS   ((DM*DI/4)/256)     // 2048
__global__ __launch_bounds__(256) void rms_split_all(
    const float* __restrict__ x, const float* __restrict__ w,
    bf16_t* __restrict__ uh, bf16_t* __restrict__ ul,
    const float* __restrict__ in_w, bf16_t* __restrict__ wih, bf16_t* __restrict__ wil,
    const float* __restrict__ x_w,  bf16_t* __restrict__ wxh,  bf16_t* __restrict__ wxl,
    const float* __restrict__ out_w, bf16_t* __restrict__ woh, bf16_t* __restrict__ wol)
{
    __shared__ float sred[4];
    int blk = blockIdx.x;
    int t = threadIdx.x;

    if (blk < NTOK) {                       // ---- RMSNorm row ----
        int row = blk;
        float4 v = ((const float4*)(x + (size_t)row*DM))[t];
        float ss = v.x*v.x + v.y*v.y + v.z*v.z + v.w*v.w;
        #pragma unroll
        for (int off = 32; off > 0; off >>= 1) ss += __shfl_xor(ss, off, 64);
        if ((t & 63) == 0) sred[t >> 6] = ss;
        __syncthreads();
        ss = sred[0] + sred[1] + sred[2] + sred[3];
        float rs = rsqrtf(ss * (1.f/(float)DM) + EPSF);
        float4 wv = ((const float4*)w)[t];
        float o[4];
        o[0] = v.x*rs*wv.x; o[1] = v.y*rs*wv.y; o[2] = v.z*rs*wv.z; o[3] = v.w*rs*wv.w;
        bf16x4 hv, lv;
        #pragma unroll
        for (int j = 0; j < 4; ++j) { hl_t s = split2(o[j]); hv[j] = s.h; lv[j] = s.l; }
        *(bf16x4*)(uh + (size_t)row*DM + t*4) = hv;
        *(bf16x4*)(ul + (size_t)row*DM + t*4) = lv;
        return;
    }
    blk -= NTOK;
    if (blk < SPLIT_IN_BLKS) {              // ---- in_proj_w ----
        int i = blk * 256 + t;
        float4 v = ((const float4*)in_w)[i];
        float o[4] = {v.x, v.y, v.z, v.w};
        bf16x4 hv, lv;
        #pragma unroll
        for (int j = 0; j < 4; ++j) { hl_t s = split2(o[j]); hv[j] = s.h; lv[j] = s.l; }
        ((bf16x4*)wih)[i] = hv;
        ((bf16x4*)wil)[i] = lv;
        return;
    }
    blk -= SPLIT_IN_BLKS;
    if (blk < SPLIT_X_BLKS) {               // ---- x_proj_w padded 96->128 ----
        int i = blk * 256 + t;              // over 128*DI/4
        int row = i >> 9;                   // DI/4 = 512 float4 per row
        bf16x4 hv, lv;
        if (row < 96) {
            float4 v = ((const float4*)x_w)[i];
            float o[4] = {v.x, v.y, v.z, v.w};
            #pragma unroll
            for (int j = 0; j < 4; ++j) { hl_t s = split2(o[j]); hv[j] = s.h; lv[j] = s.l; }
        } else {
            #pragma unroll
            for (int j = 0; j < 4; ++j) { hv[j] = (bf16_t)0.f; lv[j] = (bf16_t)0.f; }
        }
        ((bf16x4*)wxh)[i] = hv;
        ((bf16x4*)wxl)[i] = lv;
        return;
    }
    blk -= SPLIT_X_BLKS;
    {                                       // ---- out_proj_w ----
        int i = blk * 256 + t;              // over DM*DI/4
        float4 v = ((const float4*)out_w)[i];
        float o[4] = {v.x, v.y, v.z, v.w};
        bf16x4 hv, lv;
        #pragma unroll
        for (int j = 0; j < 4; ++j) { hl_t s = split2(o[j]); hv[j] = s.h; lv[j] = s.l; }
        ((bf16x4*)woh)[i] = hv;
        ((bf16x4*)wol)[i] = lv;
    }
}

// ---------------- split-bf16 MFMA NT GEMM, 2-phase double-buffered ---------
// EXACT round-4 form (no LDS swizzle — swizzle A/B'd at −2x on dt_proj, r7).
// C[M,N](fp32) = (Ah+Al)[M,K] * (Bh+Bl)[N,K]^T ; 3 MFMAs per fragment pair.
template<int BN, int EPI, bool SK>
__global__ __launch_bounds__(256) void gemm_mfma(
    const bf16_t* __restrict__ Ah, const bf16_t* __restrict__ Al,
    const bf16_t* __restrict__ Bh, const bf16_t* __restrict__ Bl,
    float* __restrict__ C, int ldc,
    const float* __restrict__ res, const float* __restrict__ bias,
    int M, int N, int K, int kspl)
{
    constexpr int NJ   = BN / 32;
    constexpr int WN   = BN / 2;
    constexpr int ACH  = 8;
    constexpr int BCH  = BN / 16;
    constexpr int NCH  = 2*ACH + 2*BCH;
    constexpr int PERW = NCH / 4;
    constexpr int AOFF_L = 128*32;
    constexpr int BOFF_H = 2*128*32;
    constexpr int BOFF_L = 2*128*32 + BN*32;
    constexpr int BUFSZ  = 2*128*32 + 2*BN*32;

    __shared__ bf16_t lds[2*BUFSZ];

    int t = threadIdx.x;
    int w = t >> 6, lane = t & 63;
    int wr = w >> 1, wc = w & 1;
    int m0 = blockIdx.y * 128;
    int n0 = SK ? 0 : blockIdx.x * BN;
    int k0beg = SK ? blockIdx.x * kspl : 0;
    int nst = (SK ? kspl : K) >> 5;
    float* Cp = C;
    if (SK) Cp += (size_t)blockIdx.x * M * BN;

    f32x4 acc[4][NJ];
    #pragma unroll
    for (int i = 0; i < 4; ++i)
        #pragma unroll
        for (int j = 0; j < NJ; ++j)
            acc[i][j] = (f32x4){0.f, 0.f, 0.f, 0.f};

    int lrow = lane >> 2;          // row within 16-row chunk
    int lcol = (lane & 3) * 8;     // k element offset (LINEAR, r4-proven)
    int ar   = wr*64 + (lane & 15);
    int br   = wc*WN + (lane & 15);
    int koff = (lane >> 4) * 8;

    auto STAGE = [&](int buf, int k0) {
        int base = buf ? BUFSZ : 0;
        #pragma unroll
        for (int q = 0; q < PERW; ++q) {
            int ch = w * PERW + q;
            const bf16_t* g; int le;
            if (ch < ACH) {
                int cc = ch;
                g  = Ah + (size_t)(m0 + cc*16 + lrow)*K + k0 + lcol;
                le = cc*512 + lane*8;
            } else if (ch < 2*ACH) {
                int cc = ch - ACH;
                g  = Al + (size_t)(m0 + cc*16 + lrow)*K + k0 + lcol;
                le = AOFF_L + cc*512 + lane*8;
            } else if (ch < 2*ACH + BCH) {
                int cc = ch - 2*ACH;
                g  = Bh + (size_t)(n0 + cc*16 + lrow)*K + k0 + lcol;
                le = BOFF_H + cc*512 + lane*8;
            } else {
                int cc = ch - 2*ACH - BCH;
                g  = Bl + (size_t)(n0 + cc*16 + lrow)*K + k0 + lcol;
                le = BOFF_L + cc*512 + lane*8;
            }
            gload_lds16(g, &lds[base + le]);
        }
    };

    STAGE(0, k0beg);
    __syncthreads();
    int cur = 0;
    for (int s = 0; s < nst; ++s) {
        int k0 = k0beg + (s << 5);
        if (s + 1 < nst) STAGE(cur ^ 1, k0 + 32);
        int base = cur ? BUFSZ : 0;

        bf16x8 ah[4], al4[4], bh[NJ], bl4[NJ];
        #pragma unroll
        for (int i = 0; i < 4; ++i) {
            ah[i]  = *(const bf16x8*)&lds[base + (ar + i*16)*32 + koff];
            al4[i] = *(const bf16x8*)&lds[base + AOFF_L + (ar + i*16)*32 + koff];
        }
        #pragma unroll
        for (int j = 0; j < NJ; ++j) {
            bh[j]  = *(const bf16x8*)&lds[base + BOFF_H + (br + j*16)*32 + koff];
            bl4[j] = *(const bf16x8*)&lds[base + BOFF_L + (br + j*16)*32 + koff];
        }
        #pragma unroll
        for (int i = 0; i < 4; ++i)
            #pragma unroll
            for (int j = 0; j < NJ; ++j) {
                acc[i][j] = __builtin_amdgcn_mfma_f32_16x16x32_bf16(ah[i],  bh[j],  acc[i][j], 0, 0, 0);
                acc[i][j] = __builtin_amdgcn_mfma_f32_16x16x32_bf16(al4[i], bh[j],  acc[i][j], 0, 0, 0);
                acc[i][j] = __builtin_amdgcn_mfma_f32_16x16x32_bf16(ah[i],  bl4[j], acc[i][j], 0, 0, 0);
            }
        __syncthreads();
        cur ^= 1;
    }

    // epilogue: C/D layout col=lane&15, row=(lane>>4)*4+reg  [m89-verified]
    int rb = m0 + wr*64 + (lane >> 4)*4;
    int cb = n0 + wc*WN + (lane & 15);
    #pragma unroll
    for (int i = 0; i < 4; ++i)
        #pragma unroll
        for (int j = 0; j < NJ; ++j) {
            int col = cb + j*16;
            #pragma unroll
            for (int r = 0; r < 4; ++r) {
                int row = rb + i*16 + r;
                float v = acc[i][j][r];
                if (EPI == 2) v += res[(size_t)row*ldc + col];
                Cp[(size_t)row*ldc + col] = v;
            }
        }
}

// ==== launch 5: x_proj reduce + fused dt_proj matvec (4 tokens/block) ======
// 512 blocks (2/CU). Phase A (threads 0..127): reduce split-K partials for
// 4 tokens into LDS dt[4][64] + write bc. Phase B (all 256): each thread
// computes 8 d-cols x 4 tokens in exact fp32, softplus, coalesced stores.
__global__ __launch_bounds__(256) void dt_fuse(
    const float* __restrict__ parts,
    float* __restrict__ bc,
    const float* __restrict__ dt_w,     // [DI, DR] fp32
    const float* __restrict__ dt_b,     // [DI]
    float* __restrict__ delta)          // [NTOK, DI]
{
    __shared__ float dtsh[4][DR];       // 1 KB
    int blk = blockIdx.x;               // 0..511
    int t = threadIdx.x;
    if (t < 128) {
        int token = t >> 5;             // 0..3
        int c = (t & 31) * 4;           // 0..124
        int m = blk*4 + token;
        float4 s = {0.f, 0.f, 0.f, 0.f};
        #pragma unroll
        for (int sp = 0; sp < SPLITS; ++sp) {
            float4 v = *(const float4*)(parts + ((size_t)sp*NTOK + m)*128 + c);
            s.x += v.x; s.y += v.y; s.z += v.z; s.w += v.w;
        }
        if (c < 64) {
            *(float4*)&dtsh[token][c] = s;
        } else if (c < 96) {
            *(float4*)(bc + (size_t)m*32 + (c - 64)) = s;
        }
    }
    __syncthreads();
    // phase B: 8 d-columns per thread, 4 tokens
    for (int dd = 0; dd < 8; ++dd) {
        int d = dd*256 + t;
        float4 wv[16];
        #pragma unroll
        for (int k4 = 0; k4 < 16; ++k4)
            wv[k4] = *(const float4*)(dt_w + (size_t)d*DR + k4*4);
        float bb = dt_b[d];
        float acc[4];
        #pragma unroll
        for (int tok = 0; tok < 4; ++tok) acc[tok] = bb;
        #pragma unroll
        for (int k4 = 0; k4 < 16; ++k4) {
            #pragma unroll
            for (int tok = 0; tok < 4; ++tok) {
                acc[tok] = fmaf(wv[k4].x, dtsh[tok][k4*4+0], acc[tok]);
                acc[tok] = fmaf(wv[k4].y, dtsh[tok][k4*4+1], acc[tok]);
                acc[tok] = fmaf(wv[k4].z, dtsh[tok][k4*4+2], acc[tok]);
                acc[tok] = fmaf(wv[k4].w, dtsh[tok][k4*4+3], acc[tok]);
            }
        }
        #pragma unroll
        for (int tok = 0; tok < 4; ++tok)
            delta[(size_t)(blk*4 + tok)*DI + d] = softplusf(acc[tok]);
    }
}

// ------- causal depthwise conv (DC=4) + bias + SiLU -> split bf16 ----------
__global__ __launch_bounds__(256) void conv_silu_k(const float* __restrict__ xz,
                                                   const float* __restrict__ cw,
                                                   const float* __restrict__ cb,
                                                   bf16_t* __restrict__ xch,
                                                   bf16_t* __restrict__ xcl)
{
    int idx = blockIdx.x * 256 + threadIdx.x;
    int d4 = idx & (DI/4 - 1);
    int m  = idx >> 9;
    int l  = m & (L_ - 1);
    int d  = d4 * 4;

    float4 w0 = *(const float4*)(cw + (size_t)(d+0)*DC);
    float4 w1 = *(const float4*)(cw + (size_t)(d+1)*DC);
    float4 w2 = *(const float4*)(cw + (size_t)(d+2)*DC);
    float4 w3 = *(const float4*)(cw + (size_t)(d+3)*DC);
    float wr0[4] = {w0.x,w0.y,w0.z,w0.w};
    float wr1[4] = {w1.x,w1.y,w1.z,w1.w};
    float wr2[4] = {w2.x,w2.y,w2.z,w2.w};
    float wr3[4] = {w3.x,w3.y,w3.z,w3.w};
    float4 bias = *(const float4*)(cb + d);
    float a0 = bias.x, a1 = bias.y, a2 = bias.z, a3 = bias.w;

    #pragma unroll
    for (int j = 0; j < DC; ++j) {
        int tt = l - (DC-1) + j;
        if (tt < 0) continue;
        float4 xv = *(const float4*)(xz + (size_t)(m - l + tt)*(2*DI) + d);
        a0 = fmaf(wr0[j], xv.x, a0);
        a1 = fmaf(wr1[j], xv.y, a1);
        a2 = fmaf(wr2[j], xv.z, a2);
        a3 = fmaf(wr3[j], xv.w, a3);
    }
    float o[4] = { siluf(a0), siluf(a1), siluf(a2), siluf(a3) };
    bf16x4 hv, lv;
    #pragma unroll
    for (int j = 0; j < 4; ++j) { hl_t s = split2(o[j]); hv[j] = s.h; lv[j] = s.l; }
    *(bf16x4*)(xch + (size_t)m*DI + d) = hv;
    *(bf16x4*)(xcl + (size_t)m*DI + d) = lv;
}

// ---------------- chunked selective scan (NC=32 chunks of CL=32) -----------
__global__ __launch_bounds__(256) void scan_p1(const float* __restrict__ delta,
                                               const bf16_t* __restrict__ xch,
                                               const bf16_t* __restrict__ xcl,
                                               const float* __restrict__ bc,
                                               const float* __restrict__ A_log,
                                               float* __restrict__ Sbuf,
                                               float* __restrict__ Hbuf)
{
    __shared__ float Bsh[CL][16];
    int t = threadIdx.x;
    int blk = blockIdx.x;                 // b*(NC*8) + c*8 + dblk
    int d = (blk & 7) * 256 + t;
    int c = (blk >> 3) & (NC - 1);
    int b = blk >> 8;
    int m0 = b * L_ + c * CL;

    for (int i = t; i < CL*16; i += 256)
        Bsh[i >> 4][i & 15] = bc[(size_t)(m0 + (i >> 4))*32 + (i & 15)];
    __syncthreads();

    float A[16], h[16];
    #pragma unroll
    for (int j = 0; j < 4; ++j) {
        float4 al = *(const float4*)(A_log + (size_t)d*DS + j*4);
        A[j*4+0] = -__expf(al.x); A[j*4+1] = -__expf(al.y);
        A[j*4+2] = -__expf(al.z); A[j*4+3] = -__expf(al.w);
    }
    #pragma unroll
    for (int n = 0; n < 16; ++n) h[n] = 0.f;
    float S = 0.f;

    #pragma unroll 4
    for (int tt = 0; tt < CL; ++tt) {
        int m = m0 + tt;
        float dv = delta[(size_t)m*DI + d];
        float xv = (float)xch[(size_t)m*DI + d] + (float)xcl[(size_t)m*DI + d];
        float dx = dv * xv;
        S += dv;
        #pragma unroll
        for (int n = 0; n < 16; ++n) {
            float dA = __expf(dv * A[n]);
            h[n] = fmaf(dA, h[n], Bsh[tt][n] * dx);
        }
    }

    Sbuf[(size_t)(b*NC + c)*DI + d] = S;
    size_t o = ((size_t)((b*NC + c)*DI) + d) * DS;
    #pragma unroll
    for (int j = 0; j < 4; ++j) {
        float4 hv;
        hv.x = h[j*4+0]; hv.y = h[j*4+1]; hv.z = h[j*4+2]; hv.w = h[j*4+3];
        *(float4*)(Hbuf + o + j*4) = hv;
    }
}

// Phase 2: scan chunk summaries per (b,d,n); P = exp(A*S) recomputed;
// Hbuf rewritten IN PLACE with h0 entering each chunk.
__global__ __launch_bounds__(256) void scan_p2(const float* __restrict__ Sbuf,
                                               float* __restrict__ Hbuf,
                                               const float* __restrict__ A_log)
{
    int idx = blockIdx.x * 256 + threadIdx.x;   // (b, d, n)
    int n = idx & 15;
    int d = (idx >> 4) & (DI - 1);
    int b = idx >> 15;
    float Areg = -__expf(A_log[(size_t)d*DS + n]);
    float h = 0.f;
    #pragma unroll
    for (int c = 0; c < NC; ++c) {
        size_t so = (size_t)(b*NC + c)*DI + d;
        size_t o  = so * DS + n;
        float P  = __expf(Areg * Sbuf[so]);
        float hh = Hbuf[o];
        Hbuf[o] = h;                 // h0 entering chunk c
        h = fmaf(P, h, hh);
    }
}

// Phase 3: replay chunk from h0, emit g = (y + xc*D)*silu(z) as split bf16.
__global__ __launch_bounds__(256) void scan_p3(const float* __restrict__ delta,
                                               const float* __restrict__ xz,
                                               const bf16_t* __restrict__ xch,
                                               const bf16_t* __restrict__ xcl,
                                               const float* __restrict__ bc,
                                               const float* __restrict__ A_log,
                                               const float* __restrict__ Dp,
                                               const float* __restrict__ h0buf,
                                               bf16_t* __restrict__ gh,
                                               bf16_t* __restrict__ gl)
{
    __shared__ float Bsh[CL][16];
    __shared__ float Csh[CL][16];
    int t = threadIdx.x;
    int blk = blockIdx.x;
    int d = (blk & 7) * 256 + t;
    int c = (blk >> 3) & (NC - 1);
    int b = blk >> 8;
    int m0 = b * L_ + c * CL;

    for (int i = t; i < CL*16; i += 256) {
        int tt = i >> 4, n = i & 15;
        size_t ro = (size_t)(m0 + tt)*32;
        Bsh[tt][n] = bc[ro + n];
        Csh[tt][n] = bc[ro + 16 + n];
    }
    __syncthreads();

    float A[16], h[16];
    #pragma unroll
    for (int j = 0; j < 4; ++j) {
        float4 al = *(const float4*)(A_log + (size_t)d*DS + j*4);
        A[j*4+0] = -__expf(al.x); A[j*4+1] = -__expf(al.y);
        A[j*4+2] = -__expf(al.z); A[j*4+3] = -__expf(al.w);
    }
    size_t o = ((size_t)((b*NC + c)*DI) + d) * DS;
    #pragma unroll
    for (int j = 0; j < 4; ++j) {
        float4 hv = *(const float4*)(h0buf + o + j*4);
        h[j*4+0] = hv.x; h[j*4+1] = hv.y; h[j*4+2] = hv.z; h[j*4+3] = hv.w;
    }
    float Dreg = Dp[d];

    for (int t0 = 0; t0 < CL; t0 += 4) {
        float dv[4], xv[4], zv[4];
        #pragma unroll
        for (int q = 0; q < 4; ++q) {
            int m = m0 + t0 + q;
            dv[q] = delta[(size_t)m*DI + d];
            xv[q] = (float)xch[(size_t)m*DI + d] + (float)xcl[(size_t)m*DI + d];
            zv[q] = xz[(size_t)m*(2*DI) + DI + d];
        }
        #pragma unroll
        for (int q = 0; q < 4; ++q) {
            int tt = t0 + q, m = m0 + tt;
            float dx = dv[q] * xv[q];
            float y = 0.f;
            #pragma unroll
            for (int n = 0; n < 16; ++n) {
                float dA = __expf(dv[q] * A[n]);
                h[n] = fmaf(dA, h[n], Bsh[tt][n] * dx);
                y = fmaf(h[n], Csh[tt][n], y);
            }
            float gv = (y + xv[q]*Dreg) * siluf(zv[q]);
            hl_t s = split2(gv);
            gh[(size_t)m*DI + d] = s.h;
            gl[(size_t)m*DI + d] = s.l;
        }
    }
}

extern "C" void kernel_launch(void* const* d_in, const int* in_sizes, int n_in,
                              void* d_out, int out_size, void* d_ws, size_t ws_size,
                              hipStream_t stream)
{
    const float* x         = (const float*)d_in[0];
    const float* norm_w    = (const float*)d_in[1];
    const float* in_proj_w = (const float*)d_in[2];
    const float* conv_w    = (const float*)d_in[3];
    const float* conv_b    = (const float*)d_in[4];
    const float* x_proj_w  = (const float*)d_in[5];
    const float* dt_proj_w = (const float*)d_in[6];
    const float* dt_proj_b = (const float*)d_in[7];
    const float* A_log     = (const float*)d_in[8];
    const float* Dp        = (const float*)d_in[9];
    const float* out_proj_w= (const float*)d_in[10];
    float* out = (float*)d_out;

    char* p = (char*)d_ws;
    float*  xz    = (float*)p;  p += (size_t)NTOK*2*DI*4;    // 33.55 MB
    bf16_t* xch   = (bf16_t*)p; p += (size_t)NTOK*DI*2;      //  8.39 MB
    bf16_t* xcl   = (bf16_t*)p; p += (size_t)NTOK*DI*2;      //  8.39 MB
    float*  delta = (float*)p;  p += (size_t)NTOK*DI*4;      // 16.78 MB
    float*  bc    = (float*)p;  p += (size_t)NTOK*32*4;      //  0.26 MB
    float*  Hbuf  = (float*)p;  p += (size_t)B_*NC*DI*DS*4;  //  8.39 MB (also uh/ul, parts)
    char*   Wreg  = p;          p += (size_t)2*DI*DM*2*2;    // 16.78 MB (wih/wil -> gh/gl)
    bf16_t* woh   = (bf16_t*)p; p += (size_t)DM*DI*2;        //  4.19 MB (dedicated)
    bf16_t* wol   = (bf16_t*)p; p += (size_t)DM*DI*2;        //  4.19 MB (dedicated)
    float*  Sbuf  = (float*)p;  p += (size_t)B_*NC*DI*4;     //  0.52 MB (dedicated)
    bf16_t* wxh   = (bf16_t*)p; p += (size_t)128*DI*2;       //  0.52 MB
    bf16_t* wxl   = (bf16_t*)p; p += (size_t)128*DI*2;       //  0.52 MB
    // total ~102.5 MB

    // Hbuf region staged reuse: uh/ul (pre-in_proj) -> parts (x_proj partials)
    // -> H/h0 (scan). Each lifetime ends before the next begins.
    bf16_t* uh  = (bf16_t*)Hbuf;
    bf16_t* ul  = uh + (size_t)NTOK*DM;
    float*  parts = Hbuf;
    // Wreg: wih/wil (in_proj weights, dead after step 2) -> gh/gl (step 6+)
    bf16_t* wih = (bf16_t*)Wreg;
    bf16_t* wil = wih + (size_t)2*DI*DM;
    bf16_t* gh  = (bf16_t*)Wreg;
    bf16_t* gl  = gh + (size_t)NTOK*DI;

    // 1. RMSNorm + all weight splits (one launch)
    rms_split_all<<<NTOK + SPLIT_IN_BLKS + SPLIT_X_BLKS + SPLIT_O_BLKS, 256, 0, stream>>>(
        x, norm_w, uh, ul, in_proj_w, wih, wil, x_proj_w, wxh, wxl,
        out_proj_w, woh, wol);

    // 2. in_proj (MFMA): xz[2048,4096] = u @ in_proj_w^T
    gemm_mfma<128,0,false><<<dim3((2*DI)/128, NTOK/128), 256, 0, stream>>>(
        uh, ul, wih, wil, xz, 2*DI, nullptr, nullptr, NTOK, 2*DI, DM, 0);

    // 3. causal depthwise conv + SiLU -> split bf16 xc
    conv_silu_k<<<(NTOK*(DI/4))/256, 256, 0, stream>>>(xz, conv_w, conv_b, xch, xcl);

    // 4. x_proj (MFMA, split-K over K=2048): parts[8][2048][128]
    gemm_mfma<128,0,true><<<dim3(SPLITS, NTOK/128), 256, 0, stream>>>(
        xch, xcl, wxh, wxl, parts, 128, nullptr, nullptr, NTOK, 128, DI, DI/SPLITS);

    // 5. reduce partials + fused dt_proj matvec (fp32), 512 blocks (2/CU)
    dt_fuse<<<NTOK/4, 256, 0, stream>>>(parts, bc, dt_proj_w, dt_proj_b, delta);

    // 6. chunked selective scan
    scan_p1<<<B_*NC*(DI/256), 256, 0, stream>>>(delta, xch, xcl, bc, A_log, Sbuf, Hbuf);
    scan_p2<<<(B_*DI*DS)/256, 256, 0, stream>>>(Sbuf, Hbuf, A_log);
    scan_p3<<<B_*NC*(DI/256), 256, 0, stream>>>(delta, xz, xch, xcl, bc, A_log, Dp,
                                                Hbuf, gh, gl);

    // 7. out_proj (MFMA) + residual: out = g @ out_proj_w^T + x
    gemm_mfma<64,2,false><<<dim3(DM/64, NTOK/128), 256, 0, stream>>>(
        gh, gl, woh, wol, out, DM, x, nullptr, NTOK, DM, DI, 0);
}